// Round 1
// baseline (29500.439 us; speedup 1.0000x reference)
//
#include <hip/hip_runtime.h>
#include <cstddef>

#define SS 256
#define BB 64
#define VV 10000
#define EE 512
#define HH 1024

// ---------------------------------------------------------------------------
// Plan (fp32 baseline):
//   1. k_init: h0_all[0], h1_all[0] <- hidden
//   2. xpart0 = Emb[inputs] @ W*0_x + b*0  (3 gather-GEMMs, K=512)
//   3. layer-0 scan: 256 x (k_rz, k_hh) using only h-part weights
//   4. xpart1 = h0_all @ W*1_x + b*1       (3 GEMMs, K=1024)
//   5. layer-1 scan: 256 x (k_rz, k_hh)
//   6. logits = h1_all @ Wout + bout       (GEMM, N=10000 guarded)
//   7. k_final: h_final -> d_out tail
// ws: xp [16384][3072] | h0_all [257][64][1024] | h1_all [257][64][1024]
//     | zbuf [64][1024] | rhbuf [64][1024]   (~337 MB)
// ---------------------------------------------------------------------------

__global__ void k_init(const float* __restrict__ hidden,
                       float* __restrict__ h0_all, float* __restrict__ h1_all) {
    int i = blockIdx.x * blockDim.x + threadIdx.x;
    if (i < BB * HH) {
        h0_all[i] = hidden[i];
        h1_all[i] = hidden[BB * HH + i];
    }
}

__global__ void k_final(const float* __restrict__ h0_all,
                        const float* __restrict__ h1_all,
                        float* __restrict__ out_tail) {
    int i = blockIdx.x * blockDim.x + threadIdx.x;
    if (i < BB * HH) {
        out_tail[i]           = h0_all[(size_t)SS * BB * HH + i];
        out_tail[BB * HH + i] = h1_all[(size_t)SS * BB * HH + i];
    }
}

// Classic 128x128 fp32 SGEMM, BK=8, 256 threads, 8x8 per thread (4+4 split).
// C[row, col] = bias[col] + sum_k Arow[k] * W[k*ldb + col]
// GATHER: A row = A + gidx[row]*lda (embedding fusion).
template<bool GATHER, bool NGUARD>
__global__ __launch_bounds__(256)
void k_gemm(const float* __restrict__ A, const int* __restrict__ gidx,
            const float* __restrict__ W, const float* __restrict__ bias,
            float* __restrict__ C, int N, int K, int lda, int ldb, size_t ldc)
{
    __shared__ float As[8][128];
    __shared__ float Bs[8][132];
    const int tid = threadIdx.x;
    const int bn = blockIdx.x, bm = blockIdx.y;
    const int tx = tid & 15, ty = tid >> 4;

    const int am = tid >> 1;        // 0..127 (A row within tile)
    const int ak = (tid & 1) * 4;   // 0 or 4
    const int grow = bm * 128 + am;
    const float* arow = GATHER ? (A + (size_t)gidx[grow] * lda)
                               : (A + (size_t)grow * lda);
    const int bk  = tid >> 5;       // 0..7
    const int bnc = (tid & 31) * 4; // 0..124
    const int gcol = bn * 128 + bnc;

    float acc[8][8];
#pragma unroll
    for (int i = 0; i < 8; ++i)
#pragma unroll
        for (int j = 0; j < 8; ++j) acc[i][j] = 0.f;

    for (int kt = 0; kt < K; kt += 8) {
        float4 av = *(const float4*)(arow + kt + ak);
        float4 bv;
        if (!NGUARD || gcol < N)
            bv = *(const float4*)(W + (size_t)(kt + bk) * ldb + gcol);
        else
            bv = make_float4(0.f, 0.f, 0.f, 0.f);
        __syncthreads();
        As[ak + 0][am] = av.x; As[ak + 1][am] = av.y;
        As[ak + 2][am] = av.z; As[ak + 3][am] = av.w;
        *(float4*)&Bs[bk][bnc] = bv;
        __syncthreads();
#pragma unroll
        for (int k = 0; k < 8; ++k) {
            float4 alo = *(const float4*)&As[k][ty * 4];
            float4 ahi = *(const float4*)&As[k][64 + ty * 4];
            float4 blo = *(const float4*)&Bs[k][tx * 4];
            float4 bhi = *(const float4*)&Bs[k][64 + tx * 4];
            float a[8] = {alo.x, alo.y, alo.z, alo.w, ahi.x, ahi.y, ahi.z, ahi.w};
            float b[8] = {blo.x, blo.y, blo.z, blo.w, bhi.x, bhi.y, bhi.z, bhi.w};
#pragma unroll
            for (int i = 0; i < 8; ++i)
#pragma unroll
                for (int j = 0; j < 8; ++j)
                    acc[i][j] += a[i] * b[j];
        }
    }
#pragma unroll
    for (int i = 0; i < 8; ++i) {
        int row = bm * 128 + ((i < 4) ? (ty * 4 + i) : (64 + ty * 4 + (i - 4)));
#pragma unroll
        for (int j = 0; j < 8; ++j) {
            int col = bn * 128 + ((j < 4) ? (tx * 4 + j) : (64 + tx * 4 + (j - 4)));
            if (!NGUARD || col < N)
                C[(size_t)row * ldc + col] = acc[i][j] + bias[col];
        }
    }
}

// Per-step r/z: block = [64 rows x 8 cols] of the 2048 (r|z) columns.
// W h-part slice staged transposed in LDS once; h read from global (L2-hot).
__global__ __launch_bounds__(256)
void k_rz(const float* __restrict__ hprev,   // [B][H]
          const float* __restrict__ xp_t,    // [B][3H] (bias folded in)
          const float* __restrict__ Wr, const float* __restrict__ Wz,
          int xoff,
          float* __restrict__ zbuf, float* __restrict__ rhbuf)
{
    __shared__ float wT[8][1028];
    const int tid = threadIdx.x;
    const int c0 = blockIdx.x * 8;     // 0..2040
    const int gate = c0 >> 10;         // 0 = r, 1 = z
    const int gc0 = c0 & 1023;
    const float* W = gate ? Wz : Wr;

    {   // stage wT[c][k] = W[(xoff+k)*H + gc0+c]
        const int c = tid & 7;
        const int k0 = (tid >> 3) * 32;
#pragma unroll 8
        for (int i = 0; i < 32; ++i)
            wT[c][k0 + i] = W[(size_t)(xoff + k0 + i) * HH + gc0 + c];
    }
    __syncthreads();

    const int c = tid & 7;
    const int col = c0 + c;
    const int r0 = (tid >> 3) * 2;
    const float* h0p = hprev + (size_t)r0 * HH;
    const float* h1p = h0p + HH;
    float acc0 = 0.f, acc1 = 0.f;
    for (int k = 0; k < HH; k += 4) {
        float4 w4 = *(const float4*)&wT[c][k];
        float4 ha = *(const float4*)(h0p + k);
        float4 hb = *(const float4*)(h1p + k);
        acc0 += ha.x * w4.x + ha.y * w4.y + ha.z * w4.z + ha.w * w4.w;
        acc1 += hb.x * w4.x + hb.y * w4.y + hb.z * w4.z + hb.w * w4.w;
    }
    float v0 = acc0 + xp_t[(size_t)r0 * 3072 + col];
    float v1 = acc1 + xp_t[(size_t)(r0 + 1) * 3072 + col];
    float s0 = 1.f / (1.f + expf(-v0));
    float s1 = 1.f / (1.f + expf(-v1));
    if (gate == 0) {
        rhbuf[(size_t)r0 * HH + col]       = s0 * h0p[col];
        rhbuf[(size_t)(r0 + 1) * HH + col] = s1 * h1p[col];
    } else {
        int gc = gc0 + c;
        zbuf[(size_t)r0 * HH + gc]       = s0;
        zbuf[(size_t)(r0 + 1) * HH + gc] = s1;
    }
}

// Per-step hh + state update: block = [64 rows x 4 cols] of 1024 columns.
__global__ __launch_bounds__(256)
void k_hh(const float* __restrict__ hprev, const float* __restrict__ xp_t,
          const float* __restrict__ Wh, int xoff,
          const float* __restrict__ zbuf, const float* __restrict__ rhbuf,
          float* __restrict__ hout)
{
    __shared__ float wT[4][1028];
    const int tid = threadIdx.x;
    const int c0 = blockIdx.x * 4;
    {
        const int c = tid & 3;
        const int k0 = (tid >> 2) * 16;
#pragma unroll 8
        for (int i = 0; i < 16; ++i)
            wT[c][k0 + i] = Wh[(size_t)(xoff + k0 + i) * HH + c0 + c];
    }
    __syncthreads();
    const int c = tid & 3;
    const int col = c0 + c;
    const int row = tid >> 2;
    const float* rh = rhbuf + (size_t)row * HH;
    float acc = 0.f;
    for (int k = 0; k < HH; k += 4) {
        float4 w4 = *(const float4*)&wT[c][k];
        float4 hv = *(const float4*)(rh + k);
        acc += hv.x * w4.x + hv.y * w4.y + hv.z * w4.z + hv.w * w4.w;
    }
    float hhv = tanhf(acc + xp_t[(size_t)row * 3072 + 2048 + col]);
    float z  = zbuf[(size_t)row * HH + col];
    float hp = hprev[(size_t)row * HH + col];
    hout[(size_t)row * HH + col] = (1.f - z) * hp + z * hhv;
}

extern "C" void kernel_launch(void* const* d_in, const int* in_sizes, int n_in,
                              void* d_out, int out_size, void* d_ws, size_t ws_size,
                              hipStream_t stream)
{
    const int*   inputs = (const int*)  d_in[0];
    const float* hidden = (const float*)d_in[1];
    const float* Emb    = (const float*)d_in[2];
    const float* Wr0 = (const float*)d_in[3];  const float* br0 = (const float*)d_in[4];
    const float* Wz0 = (const float*)d_in[5];  const float* bz0 = (const float*)d_in[6];
    const float* Wh0 = (const float*)d_in[7];  const float* bh0 = (const float*)d_in[8];
    const float* Wr1 = (const float*)d_in[9];  const float* br1 = (const float*)d_in[10];
    const float* Wz1 = (const float*)d_in[11]; const float* bz1 = (const float*)d_in[12];
    const float* Wh1 = (const float*)d_in[13]; const float* bh1 = (const float*)d_in[14];
    const float* Wout= (const float*)d_in[15]; const float* bout= (const float*)d_in[16];
    float* out = (float*)d_out;

    float* xp    = (float*)d_ws;                       // [16384][3072]
    float* h0a   = xp  + (size_t)16384 * 3072;         // [257][64][1024]
    float* h1a   = h0a + (size_t)257 * BB * HH;        // [257][64][1024]
    float* zbuf  = h1a + (size_t)257 * BB * HH;        // [64][1024]
    float* rhbuf = zbuf + (size_t)BB * HH;             // [64][1024]

    k_init<<<dim3((BB * HH) / 256), 256, 0, stream>>>(hidden, h0a, h1a);

    // xpart0: Emb-gather GEMMs, K = E = 512
    {
        dim3 g(1024 / 128, 16384 / 128);
        k_gemm<true,  false><<<g, 256, 0, stream>>>(Emb, inputs, Wr0, br0, xp + 0,    1024, EE, EE, HH, 3072);
        k_gemm<true,  false><<<g, 256, 0, stream>>>(Emb, inputs, Wz0, bz0, xp + 1024, 1024, EE, EE, HH, 3072);
        k_gemm<true,  false><<<g, 256, 0, stream>>>(Emb, inputs, Wh0, bh0, xp + 2048, 1024, EE, EE, HH, 3072);
    }
    // layer-0 scan (h-part rows start at xoff = E)
    for (int t = 0; t < SS; ++t) {
        const float* hp  = h0a + (size_t)t * BB * HH;
        const float* xpt = xp  + (size_t)t * BB * 3072;
        k_rz<<<256, 256, 0, stream>>>(hp, xpt, Wr0, Wz0, EE, zbuf, rhbuf);
        k_hh<<<256, 256, 0, stream>>>(hp, xpt, Wh0, EE, zbuf, rhbuf,
                                      h0a + (size_t)(t + 1) * BB * HH);
    }
    // xpart1: K = H, A = layer-0 outputs
    {
        dim3 g(1024 / 128, 16384 / 128);
        const float* A = h0a + (size_t)BB * HH;
        k_gemm<false, false><<<g, 256, 0, stream>>>(A, nullptr, Wr1, br1, xp + 0,    1024, HH, HH, HH, 3072);
        k_gemm<false, false><<<g, 256, 0, stream>>>(A, nullptr, Wz1, bz1, xp + 1024, 1024, HH, HH, HH, 3072);
        k_gemm<false, false><<<g, 256, 0, stream>>>(A, nullptr, Wh1, bh1, xp + 2048, 1024, HH, HH, HH, 3072);
    }
    // layer-1 scan (h-part rows start at xoff = H)
    for (int t = 0; t < SS; ++t) {
        const float* hp  = h1a + (size_t)t * BB * HH;
        const float* xpt = xp  + (size_t)t * BB * 3072;
        k_rz<<<256, 256, 0, stream>>>(hp, xpt, Wr1, Wz1, HH, zbuf, rhbuf);
        k_hh<<<256, 256, 0, stream>>>(hp, xpt, Wh1, HH, zbuf, rhbuf,
                                      h1a + (size_t)(t + 1) * BB * HH);
    }
    // logits = top @ Wout + bout
    {
        dim3 g((VV + 127) / 128, 16384 / 128);
        k_gemm<false, true><<<g, 256, 0, stream>>>(h1a + (size_t)BB * HH, nullptr,
                                                   Wout, bout, out, VV, HH, HH, VV, (size_t)VV);
    }
    k_final<<<dim3((BB * HH) / 256), 256, 0, stream>>>(h0a, h1a, out + (size_t)SS * BB * VV);
}